// Round 13
// baseline (1101.703 us; speedup 1.0000x reference)
//
#include <hip/hip_runtime.h>
#include <hip/hip_fp16.h>
#include <cstdint>

#define NLAYERS 4
#define TILE_E 32
#define GC 8

__device__ __forceinline__ float silu_f(float x){ return x / (1.f + __expf(-x)); }

// ---------------- init ----------------
__global__ void k_init(const int* __restrict__ z, const float* __restrict__ embed,
                       float* __restrict__ hs, float* __restrict__ hv, float* __restrict__ ht,
                       int* __restrict__ deg,
                       unsigned* __restrict__ mkey, float* __restrict__ den, float* __restrict__ cbuf,
                       int N, int G){
  int idx = blockIdx.x*blockDim.x + threadIdx.x;
  if (idx < N*64) hs[idx] = embed[z[idx>>6]*64 + (idx&63)];
  if (idx < N*96) hv[idx] = 0.f;
  if (idx < N*80) ht[idx] = 0.f;
  if (idx < N)   deg[idx] = 0;
  if (idx < G) { mkey[idx] = 0u; den[idx] = 0.f; }
  if (idx < G*64) cbuf[idx] = 0.f;
}

// ---------------- CSR build ----------------
__global__ void k_deg(const int* __restrict__ dst, int* __restrict__ deg, int E){
  int e = blockIdx.x*blockDim.x + threadIdx.x;
  if (e < E) atomicAdd(&deg[dst[e]], 1);
}

__global__ __launch_bounds__(256) void k_scanA(const int* __restrict__ deg, int* __restrict__ bsum, int N){
  __shared__ int red[256];
  int t = threadIdx.x;
  int idx = blockIdx.x*256 + t;
  red[t] = (idx < N) ? deg[idx] : 0;
  __syncthreads();
  for (int off=128; off>0; off>>=1){ if (t<off) red[t] += red[t+off]; __syncthreads(); }
  if (t==0) bsum[blockIdx.x] = red[0];
}

__global__ __launch_bounds__(256) void k_scanB(const int* __restrict__ bsum, int* __restrict__ boff, int nb){
  __shared__ int s[256];
  int t = threadIdx.x;
  s[t] = (t < nb) ? bsum[t] : 0;
  __syncthreads();
  for (int off=1; off<256; off<<=1){
    int v = (t>=off) ? s[t-off] : 0;
    __syncthreads();
    s[t] += v;
    __syncthreads();
  }
  if (t < nb) boff[t] = (t==0) ? 0 : s[t-1];
}

__global__ __launch_bounds__(256) void k_scanC(const int* __restrict__ deg, const int* __restrict__ boff,
                                               int* __restrict__ rowptr, int* __restrict__ cursor, int N){
  __shared__ int s[256];
  int t = threadIdx.x;
  int idx = blockIdx.x*256 + t;
  int v = (idx < N) ? deg[idx] : 0;
  s[t] = v;
  __syncthreads();
  for (int off=1; off<256; off<<=1){
    int u = (t>=off) ? s[t-off] : 0;
    __syncthreads();
    s[t] += u;
    __syncthreads();
  }
  int base = boff[blockIdx.x];
  if (idx < N){
    int ex = base + s[t] - v;
    rowptr[idx] = ex;
    cursor[idx] = ex;
    if (idx == N-1) rowptr[N] = base + s[t];
  }
}

__global__ void k_fill(const int* __restrict__ dst, const int* __restrict__ src,
                       int* __restrict__ cursor, int* __restrict__ inv, int* __restrict__ src_sorted, int E){
  int e = blockIdx.x*blockDim.x + threadIdx.x;
  if (e < E){
    int p = atomicAdd(&cursor[dst[e]], 1);
    inv[e] = p;
    src_sorted[p] = src[e];
  }
}

// ---------------- edge features in CSR order ----------------
__global__ void k_efeat(const float* __restrict__ pos, const int* __restrict__ src,
                        const int* __restrict__ dst, const int* __restrict__ inv,
                        float* __restrict__ rb_csr, float* __restrict__ y_csr, int E){
  int e = blockIdx.x*blockDim.x + threadIdx.x;
  if (e >= E) return;
  int s = src[e], d = dst[e];
  int j = inv[e];
  float vx = pos[d*3+0]-pos[s*3+0];
  float vy = pos[d*3+1]-pos[s*3+1];
  float vz = pos[d*3+2]-pos[s*3+2];
  float elen = sqrtf(vx*vx+vy*vy+vz*vz);
  float iv = 1.f/(elen+1e-9f);
  float x = vx*iv, y = vy*iv, zc = vz*iv;
  const float s3 = 1.7320508075688772f, s5 = 2.2360679774997896f, s15 = 3.872983346207417f;
  float* yp = y_csr + (size_t)j*8;   // Y1..Y8 (Y0==1 implicit)
  yp[0] = s3*x;  yp[1] = s3*y;  yp[2] = s3*zc;
  yp[3] = s15*x*y; yp[4] = s15*y*zc;
  yp[5] = 0.5f*s5*(3.f*zc*zc-1.f);
  yp[6] = s15*x*zc; yp[7] = 0.5f*s15*(x*x-y*y);
  const float sigma = 5.0f/9.0f;
  float* rp = rb_csr + (size_t)j*10;
  #pragma unroll
  for (int k=0;k<10;k++){
    float c = (5.0f/9.0f)*(float)k;
    float tt = (elen - c)/sigma;
    rp[k] = __expf(-0.5f*tt*tt);
  }
}

// ---------------- k_wgt: radial weights in CSR order, fp16 ----------------
__global__ __launch_bounds__(320) void k_wgt(
    const float* __restrict__ rb_csr,
    const float* __restrict__ rW1, const float* __restrict__ rb1, const float* __restrict__ rW2,
    __half* __restrict__ wgtbuf, int E, int l)
{
  __shared__ float hid[TILE_E][32];
  int t = threadIdx.x;
  int j0 = blockIdx.x*TILE_E;

  for (int idx=t; idx<TILE_E*32; idx+=320){
    int el = idx>>5, jj = idx&31;
    int j = j0+el;
    if (j < E){
      float acc = rb1[l*32+jj];
      const float* rbp = rb_csr + (size_t)j*10;
      const float* w1p = rW1 + (l*10)*32 + jj;
      #pragma unroll
      for (int k=0;k<10;k++) acc += rbp[k]*w1p[k*32];
      hid[el][jj] = silu_f(acc);
    }
  }
  float wcol[32];
  {
    const float* w2p = rW2 + (size_t)(l*32)*320 + t;
    #pragma unroll
    for (int jj=0;jj<32;jj++) wcol[jj] = w2p[(size_t)jj*320];
  }
  __syncthreads();

  for (int el=0; el<TILE_E; el++){
    int j = j0+el;
    if (j >= E) break;
    const float4* hrow = (const float4*)hid[el];
    float a0=0.f,a1=0.f,a2=0.f,a3=0.f;
    #pragma unroll
    for (int q=0;q<8;q++){
      float4 h4 = hrow[q];
      a0 += h4.x*wcol[q*4+0];
      a1 += h4.y*wcol[q*4+1];
      a2 += h4.z*wcol[q*4+2];
      a3 += h4.w*wcol[q*4+3];
    }
    wgtbuf[(size_t)j*320 + t] = __float2half((a0+a1)+(a2+a3));
  }
}

// ---------------- k_gather: 1 node / 256-thr block, 4 comps/thread, writes abuf (d-major) ----------------
// abuf layout per node: [0,112) a0 | [112,496) a1 as d*128+row | [496,896) a2 as d*80+row
// src-row LDS layout: [0,64) s, [64,160) v (cc*3+dd), [160,240) t (cc*5+dd)
#define ACC_JJ(jj) \
  { \
    _Pragma("unroll") \
    for (int q=0;q<4;q++){ \
      if (spec[q] < 0) continue; \
      float wg = __half2float(sWG[(jj)*320 + widx[q]]); \
      float val; \
      if (spec[q]==1){ val = sF[(jj)][off0[q]]*sY[(jj)][ds0[q]]; } \
      else if (spec[q]==0){ val = sF[(jj)][off0[q]]*sY[(jj)][ds0[q]] - sF[(jj)][off1[q]]*sY[(jj)][ds1[q]]; } \
      else if (spec[q]==2){ val = sF[(jj)][off0[q]]*sY[(jj)][0] + sF[(jj)][off0[q]+1]*sY[(jj)][1] + sF[(jj)][off0[q]+2]*sY[(jj)][2]; } \
      else { val = sF[(jj)][off0[q]]*sY[(jj)][3] + sF[(jj)][off0[q]+1]*sY[(jj)][4] + sF[(jj)][off0[q]+2]*sY[(jj)][5] \
                 + sF[(jj)][off0[q]+3]*sY[(jj)][6] + sF[(jj)][off0[q]+4]*sY[(jj)][7]; } \
      racc[q] += wg*val; \
    } \
  }

__global__ __launch_bounds__(256, 8) void k_gather(
    const float* __restrict__ hs0, const float* __restrict__ hv0, const float* __restrict__ ht0,
    float* __restrict__ abuf,
    const int* __restrict__ rowptr, const int* __restrict__ src_sorted,
    const float* __restrict__ y_csr, const __half* __restrict__ wgtbuf,
    int N, int l)
{
  __shared__ __align__(16) float smem[3328];
  float (*sF)[240] = (float(*)[240])smem;
  float (*sY)[12]  = (float(*)[12])(smem + 1920);
  __half* sWG      = (__half*)(smem + 2048);

  int t = threadIdx.x;
  int w = t>>6, lane = t&63;
  int n = blockIdx.x;
  int rs = rowptr[n], re = rowptr[n+1];

  // ---- per-thread component mapping for c = t + 256*q ----
  // spec: -1 inactive | 1 single product | 0 cross (2 products) | 2 dot3 | 3 dot5
  int widx[4], off0[4], off1[4], ds0[4], ds1[4], spec[4], opos[4];
  #pragma unroll
  for (int q=0;q<4;q++){
    int c = t + 256*q;
    spec[q] = -1; widx[q]=0; off0[q]=0; off1[q]=0; ds0[q]=8; ds1[q]=9; opos[q]=0;
    if (c < 64){            // a0 scalar : w0*s (Y0==1)
      spec[q]=1; widx[q]=c; off0[q]=c; opos[q]=c;
    } else if (c < 96){     // a0 vec dot Y1..3
      spec[q]=2; widx[q]=c; off0[q]=64+(c-64)*3; opos[q]=c;
    } else if (c < 112){    // a0 tensor dot Y4..8
      spec[q]=3; widx[q]=c; off0[q]=160+(c-96)*5; opos[q]=c;
    } else if (c < 496){
      int rr=c-112, row=rr/3, dd=rr-row*3;
      opos[q] = 112 + dd*128 + row;       // d-major a1
      if (row < 64){        // w1s * s * Y(1+dd)
        spec[q]=1; widx[q]=112+row; off0[q]=row; ds0[q]=dd;
      } else if (row < 96){ // w1v * v  (Y0==1)
        spec[q]=1; widx[q]=176+(row-64); off0[q]=64+(row-64)*3+dd;
      } else {              // w1x * cross(v, y)
        int cc=row-96;
        int d1=dd+1; if (d1>2) d1-=3;
        int d2=dd+2; if (d2>2) d2-=3;
        spec[q]=0; widx[q]=208+cc; off0[q]=64+cc*3+d1; ds0[q]=d2; off1[q]=64+cc*3+d2; ds1[q]=d1;
      }
    } else if (c < 896){
      int rr=c-496, row=rr/5, dd=rr-row*5;
      opos[q] = 496 + dd*80 + row;        // d-major a2
      if (row < 64){        // w2s * s * Y(4+dd)
        spec[q]=1; widx[q]=240+row; off0[q]=row; ds0[q]=3+dd;
      } else {              // w2t * t (Y0==1)
        spec[q]=1; widx[q]=304+(row-64); off0[q]=160+(row-64)*5+dd;
      }
    }
  }

  // ---- zero-init sF/sY (pad rows must be finite; wg=0 kills them) ----
  for (int i=t; i<2016; i+=256) smem[i] = 0.f;
  __syncthreads();

  float racc[4] = {0.f,0.f,0.f,0.f};

  for (int ch = rs; ch < re; ch += GC){
    int cnt = min(GC, re-ch);
    // ---- stage features + Y (wave w handles edges w and w+4), float4 ----
    #pragma unroll
    for (int rep=0; rep<2; rep++){
      int e = w + rep*4;
      if (e < cnt){
        int j = ch + e;
        int s_ = src_sorted[j];
        if (lane < 16){
          ((float4*)&sF[e][0])[lane] = ((const float4*)(hs0 + (size_t)s_*64))[lane];
        } else if (lane < 40){
          ((float4*)&sF[e][0])[lane] = ((const float4*)(hv0 + (size_t)s_*96))[lane-16];
        } else if (lane < 60){
          ((float4*)&sF[e][0])[lane] = ((const float4*)(ht0 + (size_t)s_*80))[lane-40];
        } else if (lane < 62){
          *(float4*)(&sY[e][(lane-60)*4]) = ((const float4*)(y_csr + (size_t)j*8))[lane-60];
        } else if (lane == 62){
          *(float4*)(&sY[e][8]) = make_float4(1.f, 0.f, 0.f, 0.f);
        }
      }
    }
    // ---- stage wgt rows (contiguous in CSR order) + zero pad rows, uint4 ----
    {
      const uint4* gsrc = (const uint4*)(wgtbuf + (size_t)ch*320);
      uint4* ldst = (uint4*)sWG;
      int tot4 = cnt*40;
      for (int i=t; i<tot4; i+=256) ldst[i] = gsrc[i];
      uint4 z4; z4.x=0u; z4.y=0u; z4.z=0u; z4.w=0u;
      for (int i=tot4+t; i<GC*40; i+=256) ldst[i] = z4;
    }
    __syncthreads();

    // ---- accumulate: 2-granular padded unroll ----
    ACC_JJ(0) ACC_JJ(1)
    if (cnt > 2){
      ACC_JJ(2) ACC_JJ(3)
      if (cnt > 4){
        ACC_JJ(4) ACC_JJ(5)
        if (cnt > 6){
          ACC_JJ(6) ACC_JJ(7)
        }
      }
    }
    __syncthreads();
  }

  // ---- write aggregated messages (d-major permutation) ----
  float* ap = abuf + (size_t)n*896;
  ap[opos[0]] = racc[0];
  ap[opos[1]] = racc[1];
  ap[opos[2]] = racc[2];
  if (t < 128) ap[opos[3]] = racc[3];
}

// ---------------- k_update: barrier-free streaming, 4 nodes per thread ----------------
#define FMA4(acc, s, wv4) { acc.x += (s)*(wv4).x; acc.y += (s)*(wv4).y; acc.z += (s)*(wv4).z; acc.w += (s)*(wv4).w; }

__global__ __launch_bounds__(256) void k_update(
    const float* __restrict__ hs0, const float* __restrict__ hv0, const float* __restrict__ ht0,
    float* __restrict__ hs1, float* __restrict__ hv1, float* __restrict__ ht1,
    const float* __restrict__ abuf,
    const float* __restrict__ Ws, const float* __restrict__ Wss,
    const float* __restrict__ Wv, const float* __restrict__ Wvv,
    const float* __restrict__ Wt, const float* __restrict__ Wtt,
    int N, int l)
{
  int nquads = (N+3)>>2;
  int task = blockIdx.x*256 + threadIdx.x;
  int limA = nquads*16, limB = nquads*40, limC = nquads*60;

  if (task < limA){
    int nq = task >> 4, fg = task & 15;
    int n0 = nq*4;
    int m1 = min(n0+1,N-1), m2 = min(n0+2,N-1), m3 = min(n0+3,N-1);
    const float4* A0 = (const float4*)(abuf + (size_t)n0*896);
    const float4* A1 = (const float4*)(abuf + (size_t)m1*896);
    const float4* A2 = (const float4*)(abuf + (size_t)m2*896);
    const float4* A3 = (const float4*)(abuf + (size_t)m3*896);
    const float* Wsg = Ws + (size_t)l*112*64 + fg*4;
    float4 c0={0.f,0.f,0.f,0.f}, c1=c0, c2=c0, c3=c0;
    #pragma unroll 2
    for (int cb=0; cb<28; cb++){
      const float* wp = Wsg + (size_t)(cb*4)*64;
      float4 w0 = *(const float4*)(wp);
      float4 w1 = *(const float4*)(wp+64);
      float4 w2 = *(const float4*)(wp+128);
      float4 w3 = *(const float4*)(wp+192);
      float4 a0 = A0[cb], a1 = A1[cb], a2 = A2[cb], a3 = A3[cb];
      FMA4(c0,a0.x,w0); FMA4(c0,a0.y,w1); FMA4(c0,a0.z,w2); FMA4(c0,a0.w,w3);
      FMA4(c1,a1.x,w0); FMA4(c1,a1.y,w1); FMA4(c1,a1.z,w2); FMA4(c1,a1.w,w3);
      FMA4(c2,a2.x,w0); FMA4(c2,a2.y,w1); FMA4(c2,a2.z,w2); FMA4(c2,a2.w,w3);
      FMA4(c3,a3.x,w0); FMA4(c3,a3.y,w1); FMA4(c3,a3.z,w2); FMA4(c3,a3.w,w3);
    }
    const float4* H0 = (const float4*)(hs0 + (size_t)n0*64);
    const float4* H1 = (const float4*)(hs0 + (size_t)m1*64);
    const float4* H2 = (const float4*)(hs0 + (size_t)m2*64);
    const float4* H3 = (const float4*)(hs0 + (size_t)m3*64);
    const float* Wssg = Wss + (size_t)l*64*64 + fg*4;
    #pragma unroll 2
    for (int cb=0; cb<16; cb++){
      const float* wp = Wssg + (size_t)(cb*4)*64;
      float4 w0 = *(const float4*)(wp);
      float4 w1 = *(const float4*)(wp+64);
      float4 w2 = *(const float4*)(wp+128);
      float4 w3 = *(const float4*)(wp+192);
      float4 a0 = H0[cb], a1 = H1[cb], a2 = H2[cb], a3 = H3[cb];
      FMA4(c0,a0.x,w0); FMA4(c0,a0.y,w1); FMA4(c0,a0.z,w2); FMA4(c0,a0.w,w3);
      FMA4(c1,a1.x,w0); FMA4(c1,a1.y,w1); FMA4(c1,a1.z,w2); FMA4(c1,a1.w,w3);
      FMA4(c2,a2.x,w0); FMA4(c2,a2.y,w1); FMA4(c2,a2.z,w2); FMA4(c2,a2.w,w3);
      FMA4(c3,a3.x,w0); FMA4(c3,a3.y,w1); FMA4(c3,a3.z,w2); FMA4(c3,a3.w,w3);
    }
    float4 o;
    o.x=silu_f(c0.x); o.y=silu_f(c0.y); o.z=silu_f(c0.z); o.w=silu_f(c0.w);
    *(float4*)(hs1 + (size_t)n0*64 + fg*4) = o;
    if (n0+1 < N){ o.x=silu_f(c1.x); o.y=silu_f(c1.y); o.z=silu_f(c1.z); o.w=silu_f(c1.w); *(float4*)(hs1 + (size_t)(n0+1)*64 + fg*4) = o; }
    if (n0+2 < N){ o.x=silu_f(c2.x); o.y=silu_f(c2.y); o.z=silu_f(c2.z); o.w=silu_f(c2.w); *(float4*)(hs1 + (size_t)(n0+2)*64 + fg*4) = o; }
    if (n0+3 < N){ o.x=silu_f(c3.x); o.y=silu_f(c3.y); o.z=silu_f(c3.z); o.w=silu_f(c3.w); *(float4*)(hs1 + (size_t)(n0+3)*64 + fg*4) = o; }
  } else if (task < limB){
    int tB = task - limA;
    int nq = tB / 24, r = tB - nq*24;
    int d = r >> 3, fg = r & 7;          // f = fg*4
    int n0 = nq*4;
    int m1 = min(n0+1,N-1), m2 = min(n0+2,N-1), m3 = min(n0+3,N-1);
    const float4* A0 = (const float4*)(abuf + (size_t)n0*896 + 112 + d*128);
    const float4* A1 = (const float4*)(abuf + (size_t)m1*896 + 112 + d*128);
    const float4* A2 = (const float4*)(abuf + (size_t)m2*896 + 112 + d*128);
    const float4* A3 = (const float4*)(abuf + (size_t)m3*896 + 112 + d*128);
    const float* Wvg = Wv + (size_t)l*128*32 + fg*4;
    float4 c0={0.f,0.f,0.f,0.f}, c1=c0, c2=c0, c3=c0;
    #pragma unroll 2
    for (int cb=0; cb<32; cb++){
      const float* wp = Wvg + (size_t)(cb*4)*32;
      float4 w0 = *(const float4*)(wp);
      float4 w1 = *(const float4*)(wp+32);
      float4 w2 = *(const float4*)(wp+64);
      float4 w3 = *(const float4*)(wp+96);
      float4 a0 = A0[cb], a1 = A1[cb], a2 = A2[cb], a3 = A3[cb];
      FMA4(c0,a0.x,w0); FMA4(c0,a0.y,w1); FMA4(c0,a0.z,w2); FMA4(c0,a0.w,w3);
      FMA4(c1,a1.x,w0); FMA4(c1,a1.y,w1); FMA4(c1,a1.z,w2); FMA4(c1,a1.w,w3);
      FMA4(c2,a2.x,w0); FMA4(c2,a2.y,w1); FMA4(c2,a2.z,w2); FMA4(c2,a2.w,w3);
      FMA4(c3,a3.x,w0); FMA4(c3,a3.y,w1); FMA4(c3,a3.z,w2); FMA4(c3,a3.w,w3);
    }
    const float* h0 = hv0 + (size_t)n0*96 + d;
    const float* h1 = hv0 + (size_t)m1*96 + d;
    const float* h2 = hv0 + (size_t)m2*96 + d;
    const float* h3 = hv0 + (size_t)m3*96 + d;
    const float* Wvvg = Wvv + (size_t)l*32*32 + fg*4;
    #pragma unroll 2
    for (int cc=0; cc<32; cc++){
      float4 wv4 = *(const float4*)(Wvvg + (size_t)cc*32);
      float a0 = h0[cc*3], a1 = h1[cc*3], a2 = h2[cc*3], a3 = h3[cc*3];
      FMA4(c0,a0,wv4); FMA4(c1,a1,wv4); FMA4(c2,a2,wv4); FMA4(c3,a3,wv4);
    }
    int f = fg*4;
    {
      float* op = hv1 + (size_t)n0*96 + d;
      op[(f+0)*3]=c0.x; op[(f+1)*3]=c0.y; op[(f+2)*3]=c0.z; op[(f+3)*3]=c0.w;
    }
    if (n0+1 < N){ float* op = hv1 + (size_t)(n0+1)*96 + d; op[(f+0)*3]=c1.x; op[(f+1)*3]=c1.y; op[(f+2)*3]=c1.z; op[(f+3)*3]=c1.w; }
    if (n0+2 < N){ float* op = hv1 + (size_t)(n0+2)*96 + d; op[(f+0)*3]=c2.x; op[(f+1)*3]=c2.y; op[(f+2)*3]=c2.z; op[(f+3)*3]=c2.w; }
    if (n0+3 < N){ float* op = hv1 + (size_t)(n0+3)*96 + d; op[(f+0)*3]=c3.x; op[(f+1)*3]=c3.y; op[(f+2)*3]=c3.z; op[(f+3)*3]=c3.w; }
  } else if (task < limC){
    int tC = task - limB;
    int nq = tC / 20, r = tC - nq*20;
    int d = r >> 2, fg = r & 3;          // f = fg*4
    int n0 = nq*4;
    int m1 = min(n0+1,N-1), m2 = min(n0+2,N-1), m3 = min(n0+3,N-1);
    const float4* A0 = (const float4*)(abuf + (size_t)n0*896 + 496 + d*80);
    const float4* A1 = (const float4*)(abuf + (size_t)m1*896 + 496 + d*80);
    const float4* A2 = (const float4*)(abuf + (size_t)m2*896 + 496 + d*80);
    const float4* A3 = (const float4*)(abuf + (size_t)m3*896 + 496 + d*80);
    const float* Wtg = Wt + (size_t)l*80*16 + fg*4;
    float4 c0={0.f,0.f,0.f,0.f}, c1=c0, c2=c0, c3=c0;
    #pragma unroll 2
    for (int cb=0; cb<20; cb++){
      const float* wp = Wtg + (size_t)(cb*4)*16;
      float4 w0 = *(const float4*)(wp);
      float4 w1 = *(const float4*)(wp+16);
      float4 w2 = *(const float4*)(wp+32);
      float4 w3 = *(const float4*)(wp+48);
      float4 a0 = A0[cb], a1 = A1[cb], a2 = A2[cb], a3 = A3[cb];
      FMA4(c0,a0.x,w0); FMA4(c0,a0.y,w1); FMA4(c0,a0.z,w2); FMA4(c0,a0.w,w3);
      FMA4(c1,a1.x,w0); FMA4(c1,a1.y,w1); FMA4(c1,a1.z,w2); FMA4(c1,a1.w,w3);
      FMA4(c2,a2.x,w0); FMA4(c2,a2.y,w1); FMA4(c2,a2.z,w2); FMA4(c2,a2.w,w3);
      FMA4(c3,a3.x,w0); FMA4(c3,a3.y,w1); FMA4(c3,a3.z,w2); FMA4(c3,a3.w,w3);
    }
    const float* h0 = ht0 + (size_t)n0*80 + d;
    const float* h1 = ht0 + (size_t)m1*80 + d;
    const float* h2 = ht0 + (size_t)m2*80 + d;
    const float* h3 = ht0 + (size_t)m3*80 + d;
    const float* Wttg = Wtt + (size_t)l*16*16 + fg*4;
    #pragma unroll 2
    for (int cc=0; cc<16; cc++){
      float4 wv4 = *(const float4*)(Wttg + (size_t)cc*16);
      float a0 = h0[cc*5], a1 = h1[cc*5], a2 = h2[cc*5], a3 = h3[cc*5];
      FMA4(c0,a0,wv4); FMA4(c1,a1,wv4); FMA4(c2,a2,wv4); FMA4(c3,a3,wv4);
    }
    int f = fg*4;
    {
      float* op = ht1 + (size_t)n0*80 + d;
      op[(f+0)*5]=c0.x; op[(f+1)*5]=c0.y; op[(f+2)*5]=c0.z; op[(f+3)*5]=c0.w;
    }
    if (n0+1 < N){ float* op = ht1 + (size_t)(n0+1)*80 + d; op[(f+0)*5]=c1.x; op[(f+1)*5]=c1.y; op[(f+2)*5]=c1.z; op[(f+3)*5]=c1.w; }
    if (n0+2 < N){ float* op = ht1 + (size_t)(n0+2)*80 + d; op[(f+0)*5]=c2.x; op[(f+1)*5]=c2.y; op[(f+2)*5]=c2.z; op[(f+3)*5]=c2.w; }
    if (n0+3 < N){ float* op = ht1 + (size_t)(n0+3)*80 + d; op[(f+0)*5]=c3.x; op[(f+1)*5]=c3.y; op[(f+2)*5]=c3.z; op[(f+3)*5]=c3.w; }
  }
}

// ---------------- readout ----------------
__global__ __launch_bounds__(64) void k_q(const float* __restrict__ hs, const int* __restrict__ absorber,
                                          const float* __restrict__ Wq, float* __restrict__ qbuf, int G){
  __shared__ float sH[64];
  int g = blockIdx.x, f = threadIdx.x;
  int a = absorber[g];
  sH[f] = hs[(size_t)a*64+f];
  __syncthreads();
  float acc = 0.f;
  for (int c=0;c<64;c++) acc += sH[c]*Wq[c*64+f];
  qbuf[(size_t)g*64+f] = acc;
}

__global__ __launch_bounds__(64) void k_kv(const float* __restrict__ hs,
                                           const float* __restrict__ Wk, const float* __restrict__ Wvp,
                                           float* __restrict__ kbuf, float* __restrict__ vbuf, int N){
  __shared__ float sH[8][64];
  int t = threadIdx.x;
  int n0 = blockIdx.x*8;
  int nmax = min(8, N-n0);
  for (int idx=t; idx<nmax*64; idx+=64){ int n=idx>>6, c=idx&63; sH[n][c]=hs[(size_t)(n0+n)*64+c]; }
  __syncthreads();
  float ka[8], va[8];
  #pragma unroll
  for (int n=0;n<8;n++){ ka[n]=0.f; va[n]=0.f; }
  for (int c=0;c<64;c++){
    float wk = Wk[c*64+t], wv = Wvp[c*64+t];
    #pragma unroll
    for (int n=0;n<8;n++){ ka[n]+=sH[n][c]*wk; va[n]+=sH[n][c]*wv; }
  }
  for (int n=0;n<nmax;n++){ kbuf[(size_t)(n0+n)*64+t]=ka[n]; vbuf[(size_t)(n0+n)*64+t]=va[n]; }
}

__global__ __launch_bounds__(256) void k_logit(const float* __restrict__ kbuf, const float* __restrict__ qbuf,
                                               const int* __restrict__ batch,
                                               float* __restrict__ logitbuf, unsigned* __restrict__ mkey, int N){
  int wave = threadIdx.x>>6, lane = threadIdx.x&63;
  int n = blockIdx.x*4 + wave;
  if (n >= N) return;
  int g = batch[n];
  float p = kbuf[(size_t)n*64+lane]*qbuf[(size_t)g*64+lane];
  #pragma unroll
  for (int off=32; off>0; off>>=1) p += __shfl_down(p, off, 64);
  if (lane==0){
    float logit = p*0.125f;
    logitbuf[n] = logit;
    unsigned u = __float_as_uint(logit);
    unsigned key = (u & 0x80000000u) ? ~u : (u | 0x80000000u);
    atomicMax(&mkey[g], key);
  }
}

__global__ __launch_bounds__(256) void k_soft(const float* __restrict__ vbuf, const float* __restrict__ logitbuf,
                                              const int* __restrict__ batch, const unsigned* __restrict__ mkey,
                                              float* __restrict__ den, float* __restrict__ cbuf, int N){
  int wave = threadIdx.x>>6, lane = threadIdx.x&63;
  int n = blockIdx.x*4 + wave;
  if (n >= N) return;
  int g = batch[n];
  unsigned key = mkey[g];
  unsigned u = (key & 0x80000000u) ? (key ^ 0x80000000u) : ~key;
  float m = __uint_as_float(u);
  float ex = __expf(logitbuf[n] - m);
  if (lane==0) atomicAdd(&den[g], ex);
  atomicAdd(&cbuf[(size_t)g*64+lane], ex*vbuf[(size_t)n*64+lane]);
}

__global__ __launch_bounds__(192) void k_final(const float* __restrict__ hs, const float* __restrict__ hv,
                                               const float* __restrict__ ht, const int* __restrict__ absorber,
                                               const float* __restrict__ den, const float* __restrict__ cbuf,
                                               const float* __restrict__ Wr1, const float* __restrict__ br1,
                                               const float* __restrict__ Wr2, const float* __restrict__ br2,
                                               float* __restrict__ out, int G){
  __shared__ float zr[176];
  __shared__ float h1[128];
  int g = blockIdx.x, t = threadIdx.x;
  int a = absorber[g];
  if (t < 64) zr[t] = hs[(size_t)a*64+t];
  else if (t < 128){
    int f = t-64;
    zr[t] = cbuf[(size_t)g*64+f] / fmaxf(den[g], 1e-9f);
  } else if (t < 160){
    int j = t-128; float s = 0.f;
    #pragma unroll
    for (int dd=0;dd<3;dd++){ float v = hv[(size_t)a*96+j*3+dd]; s += v*v; }
    zr[t] = s;
  } else if (t < 176){
    int j = t-160; float s = 0.f;
    #pragma unroll
    for (int dd=0;dd<5;dd++){ float v = ht[(size_t)a*80+j*5+dd]; s += v*v; }
    zr[t] = s;
  }
  __syncthreads();
  if (t < 128){
    float acc = br1[t];
    for (int i=0;i<176;i++) acc += zr[i]*Wr1[i*128+t];
    h1[t] = silu_f(acc);
  }
  __syncthreads();
  if (t < 128){
    float acc = br2[t];
    for (int j=0;j<128;j++) acc += h1[j]*Wr2[j*128+t];
    out[(size_t)g*128+t] = acc;
  }
}

extern "C" void kernel_launch(void* const* d_in, const int* in_sizes, int n_in,
                              void* d_out, int out_size, void* d_ws, size_t ws_size,
                              hipStream_t stream){
  const int*   z        = (const int*)  d_in[0];
  const float* pos      = (const float*)d_in[1];
  const int*   ei       = (const int*)  d_in[2];
  const int*   batch    = (const int*)  d_in[3];
  const int*   absorber = (const int*)  d_in[4];
  const float* embed    = (const float*)d_in[5];
  const float* rW1      = (const float*)d_in[6];
  const float* rb1      = (const float*)d_in[7];
  const float* rW2      = (const float*)d_in[8];
  const float* Ws       = (const float*)d_in[9];
  const float* Wss      = (const float*)d_in[10];
  const float* Wv       = (const float*)d_in[11];
  const float* Wvv      = (const float*)d_in[12];
  const float* Wt       = (const float*)d_in[13];
  const float* Wtt      = (const float*)d_in[14];
  const float* Wq       = (const float*)d_in[15];
  const float* Wk       = (const float*)d_in[16];
  const float* Wvp      = (const float*)d_in[17];
  const float* Wr1      = (const float*)d_in[18];
  const float* br1      = (const float*)d_in[19];
  const float* Wr2      = (const float*)d_in[20];
  const float* br2      = (const float*)d_in[21];

  int N = in_sizes[0];
  int E = in_sizes[2]/2;
  int G = in_sizes[4];
  const int* srcArr = ei;
  const int* dstArr = ei + E;

  float* p = (float*)d_ws;
  float* hsA   = p; p += (size_t)N*64;
  float* hvA   = p; p += (size_t)N*96;
  float* htA   = p; p += (size_t)N*80;
  float* hsB   = p; p += (size_t)N*64;
  float* hvB   = p; p += (size_t)N*96;
  float* htB   = p; p += (size_t)N*80;
  float* rb_csr= p; p += (size_t)E*10;
  float* y_csr = p; p += (size_t)E*8;
  unsigned* mkey = (unsigned*)p; p += G;
  float* den   = p; p += G;
  float* cbuf  = p; p += (size_t)G*64;
  int* deg     = (int*)p; p += N;
  int* rowptr  = (int*)p; p += (N+1);
  int* cursor  = (int*)p; p += N;
  int* inv     = (int*)p; p += E;
  int* src_sorted = (int*)p; p += E;
  int* bsum    = (int*)p; p += 256;
  int* boff    = (int*)p; p += 256;
  p += ((8 - (((uintptr_t)p >> 2) & 7)) & 7);   // 32B align
  __half* wgtbuf = (__half*)p;                   // E*320 halves = E*160 floats
  float* kbuf    = (float*)wgtbuf;               // readout aliases (post-layers)
  float* vbuf    = kbuf + (size_t)N*64;
  float* qbuf    = vbuf + (size_t)N*64;
  float* logitbuf= qbuf + (size_t)G*64;
  p += (size_t)E*160;
  float* abuf  = p; p += (size_t)N*896;

  int nb = (N + 255)/256;
  int initTot = N*96;
  k_init<<<(initTot+255)/256, 256, 0, stream>>>(z, embed, hsA, hvA, htA, deg, mkey, den, cbuf, N, G);
  k_deg<<<(E+255)/256, 256, 0, stream>>>(dstArr, deg, E);
  k_scanA<<<nb, 256, 0, stream>>>(deg, bsum, N);
  k_scanB<<<1, 256, 0, stream>>>(bsum, boff, nb);
  k_scanC<<<nb, 256, 0, stream>>>(deg, boff, rowptr, cursor, N);
  k_fill<<<(E+255)/256, 256, 0, stream>>>(dstArr, srcArr, cursor, inv, src_sorted, E);
  k_efeat<<<(E+255)/256, 256, 0, stream>>>(pos, srcArr, dstArr, inv, rb_csr, y_csr, E);

  float *hsO=hsA, *hvO=hvA, *htO=htA, *hsN=hsB, *hvN=hvB, *htN=htB;
  int nquads = (N+3)/4;
  int updBlocks = (nquads*60 + 255)/256;
  for (int l=0; l<NLAYERS; l++){
    k_wgt<<<(E+TILE_E-1)/TILE_E, 320, 0, stream>>>(rb_csr, rW1, rb1, rW2, wgtbuf, E, l);
    k_gather<<<N, 256, 0, stream>>>(hsO, hvO, htO, abuf,
                                    rowptr, src_sorted, y_csr, wgtbuf, N, l);
    k_update<<<updBlocks, 256, 0, stream>>>(hsO, hvO, htO, hsN, hvN, htN, abuf,
                                            Ws, Wss, Wv, Wvv, Wt, Wtt, N, l);
    float* tp;
    tp=hsO; hsO=hsN; hsN=tp;
    tp=hvO; hvO=hvN; hvN=tp;
    tp=htO; htO=htN; htN=tp;
  }

  k_q<<<G, 64, 0, stream>>>(hsO, absorber, Wq, qbuf, G);
  k_kv<<<(N+7)/8, 64, 0, stream>>>(hsO, Wk, Wvp, kbuf, vbuf, N);
  k_logit<<<(N+3)/4, 256, 0, stream>>>(kbuf, qbuf, batch, logitbuf, mkey, N);
  k_soft<<<(N+3)/4, 256, 0, stream>>>(vbuf, logitbuf, batch, mkey, den, cbuf, N);
  k_final<<<G, 192, 0, stream>>>(hsO, hvO, htO, absorber, den, cbuf, Wr1, br1, Wr2, br2, (float*)d_out, G);
}

// Round 14
// 1001.570 us; speedup vs baseline: 1.1000x; 1.1000x over previous
//
#include <hip/hip_runtime.h>
#include <hip/hip_fp16.h>
#include <cstdint>

#define NLAYERS 4
#define TILE_E 32
#define GC 8

__device__ __forceinline__ float silu_f(float x){ return x / (1.f + __expf(-x)); }

// ---------------- init ----------------
__global__ void k_init(const int* __restrict__ z, const float* __restrict__ embed,
                       float* __restrict__ hs, float* __restrict__ hv, float* __restrict__ ht,
                       int* __restrict__ deg,
                       unsigned* __restrict__ mkey, float* __restrict__ den, float* __restrict__ cbuf,
                       int N, int G){
  int idx = blockIdx.x*blockDim.x + threadIdx.x;
  if (idx < N*64) hs[idx] = embed[z[idx>>6]*64 + (idx&63)];
  if (idx < N*96) hv[idx] = 0.f;
  if (idx < N*80) ht[idx] = 0.f;
  if (idx < N)   deg[idx] = 0;
  if (idx < G) { mkey[idx] = 0u; den[idx] = 0.f; }
  if (idx < G*64) cbuf[idx] = 0.f;
}

// ---------------- CSR build ----------------
__global__ void k_deg(const int* __restrict__ dst, int* __restrict__ deg, int E){
  int e = blockIdx.x*blockDim.x + threadIdx.x;
  if (e < E) atomicAdd(&deg[dst[e]], 1);
}

__global__ __launch_bounds__(256) void k_scanA(const int* __restrict__ deg, int* __restrict__ bsum, int N){
  __shared__ int red[256];
  int t = threadIdx.x;
  int idx = blockIdx.x*256 + t;
  red[t] = (idx < N) ? deg[idx] : 0;
  __syncthreads();
  for (int off=128; off>0; off>>=1){ if (t<off) red[t] += red[t+off]; __syncthreads(); }
  if (t==0) bsum[blockIdx.x] = red[0];
}

__global__ __launch_bounds__(256) void k_scanB(const int* __restrict__ bsum, int* __restrict__ boff, int nb){
  __shared__ int s[256];
  int t = threadIdx.x;
  s[t] = (t < nb) ? bsum[t] : 0;
  __syncthreads();
  for (int off=1; off<256; off<<=1){
    int v = (t>=off) ? s[t-off] : 0;
    __syncthreads();
    s[t] += v;
    __syncthreads();
  }
  if (t < nb) boff[t] = (t==0) ? 0 : s[t-1];
}

__global__ __launch_bounds__(256) void k_scanC(const int* __restrict__ deg, const int* __restrict__ boff,
                                               int* __restrict__ rowptr, int* __restrict__ cursor, int N){
  __shared__ int s[256];
  int t = threadIdx.x;
  int idx = blockIdx.x*256 + t;
  int v = (idx < N) ? deg[idx] : 0;
  s[t] = v;
  __syncthreads();
  for (int off=1; off<256; off<<=1){
    int u = (t>=off) ? s[t-off] : 0;
    __syncthreads();
    s[t] += u;
    __syncthreads();
  }
  int base = boff[blockIdx.x];
  if (idx < N){
    int ex = base + s[t] - v;
    rowptr[idx] = ex;
    cursor[idx] = ex;
    if (idx == N-1) rowptr[N] = base + s[t];
  }
}

__global__ void k_fill(const int* __restrict__ dst, const int* __restrict__ src,
                       int* __restrict__ cursor, int* __restrict__ inv, int* __restrict__ src_sorted, int E){
  int e = blockIdx.x*blockDim.x + threadIdx.x;
  if (e < E){
    int p = atomicAdd(&cursor[dst[e]], 1);
    inv[e] = p;
    src_sorted[p] = src[e];
  }
}

// ---------------- edge features in CSR order ----------------
__global__ void k_efeat(const float* __restrict__ pos, const int* __restrict__ src,
                        const int* __restrict__ dst, const int* __restrict__ inv,
                        float* __restrict__ rb_csr, float* __restrict__ y_csr, int E){
  int e = blockIdx.x*blockDim.x + threadIdx.x;
  if (e >= E) return;
  int s = src[e], d = dst[e];
  int j = inv[e];
  float vx = pos[d*3+0]-pos[s*3+0];
  float vy = pos[d*3+1]-pos[s*3+1];
  float vz = pos[d*3+2]-pos[s*3+2];
  float elen = sqrtf(vx*vx+vy*vy+vz*vz);
  float iv = 1.f/(elen+1e-9f);
  float x = vx*iv, y = vy*iv, zc = vz*iv;
  const float s3 = 1.7320508075688772f, s5 = 2.2360679774997896f, s15 = 3.872983346207417f;
  float* yp = y_csr + (size_t)j*8;   // Y1..Y8 (Y0==1 implicit)
  yp[0] = s3*x;  yp[1] = s3*y;  yp[2] = s3*zc;
  yp[3] = s15*x*y; yp[4] = s15*y*zc;
  yp[5] = 0.5f*s5*(3.f*zc*zc-1.f);
  yp[6] = s15*x*zc; yp[7] = 0.5f*s15*(x*x-y*y);
  const float sigma = 5.0f/9.0f;
  float* rp = rb_csr + (size_t)j*10;
  #pragma unroll
  for (int k=0;k<10;k++){
    float c = (5.0f/9.0f)*(float)k;
    float tt = (elen - c)/sigma;
    rp[k] = __expf(-0.5f*tt*tt);
  }
}

// ---------------- k_wgt: radial weights in CSR order, fp16 ----------------
__global__ __launch_bounds__(320) void k_wgt(
    const float* __restrict__ rb_csr,
    const float* __restrict__ rW1, const float* __restrict__ rb1, const float* __restrict__ rW2,
    __half* __restrict__ wgtbuf, int E, int l)
{
  __shared__ float hid[TILE_E][32];
  int t = threadIdx.x;
  int j0 = blockIdx.x*TILE_E;

  for (int idx=t; idx<TILE_E*32; idx+=320){
    int el = idx>>5, jj = idx&31;
    int j = j0+el;
    if (j < E){
      float acc = rb1[l*32+jj];
      const float* rbp = rb_csr + (size_t)j*10;
      const float* w1p = rW1 + (l*10)*32 + jj;
      #pragma unroll
      for (int k=0;k<10;k++) acc += rbp[k]*w1p[k*32];
      hid[el][jj] = silu_f(acc);
    }
  }
  float wcol[32];
  {
    const float* w2p = rW2 + (size_t)(l*32)*320 + t;
    #pragma unroll
    for (int jj=0;jj<32;jj++) wcol[jj] = w2p[(size_t)jj*320];
  }
  __syncthreads();

  for (int el=0; el<TILE_E; el++){
    int j = j0+el;
    if (j >= E) break;
    const float4* hrow = (const float4*)hid[el];
    float a0=0.f,a1=0.f,a2=0.f,a3=0.f;
    #pragma unroll
    for (int q=0;q<8;q++){
      float4 h4 = hrow[q];
      a0 += h4.x*wcol[q*4+0];
      a1 += h4.y*wcol[q*4+1];
      a2 += h4.z*wcol[q*4+2];
      a3 += h4.w*wcol[q*4+3];
    }
    wgtbuf[(size_t)j*320 + t] = __float2half((a0+a1)+(a2+a3));
  }
}

// ---------------- k_gather: 1 node / 256-thr block, 4 comps/thread, writes abuf (d-major) ----------------
// abuf layout per node: [0,112) a0 | [112,496) a1 as d*128+row | [496,896) a2 as d*80+row
// src-row LDS layout: [0,64) s, [64,160) v (cc*3+dd), [160,240) t (cc*5+dd)
#define ACC_JJ(jj) \
  { \
    _Pragma("unroll") \
    for (int q=0;q<4;q++){ \
      if (spec[q] < 0) continue; \
      float wg = __half2float(sWG[(jj)*320 + widx[q]]); \
      float val; \
      if (spec[q]==1){ val = sF[(jj)][off0[q]]*sY[(jj)][ds0[q]]; } \
      else if (spec[q]==0){ val = sF[(jj)][off0[q]]*sY[(jj)][ds0[q]] - sF[(jj)][off1[q]]*sY[(jj)][ds1[q]]; } \
      else if (spec[q]==2){ val = sF[(jj)][off0[q]]*sY[(jj)][0] + sF[(jj)][off0[q]+1]*sY[(jj)][1] + sF[(jj)][off0[q]+2]*sY[(jj)][2]; } \
      else { val = sF[(jj)][off0[q]]*sY[(jj)][3] + sF[(jj)][off0[q]+1]*sY[(jj)][4] + sF[(jj)][off0[q]+2]*sY[(jj)][5] \
                 + sF[(jj)][off0[q]+3]*sY[(jj)][6] + sF[(jj)][off0[q]+4]*sY[(jj)][7]; } \
      racc[q] += wg*val; \
    } \
  }

__global__ __launch_bounds__(256, 8) void k_gather(
    const float* __restrict__ hs0, const float* __restrict__ hv0, const float* __restrict__ ht0,
    float* __restrict__ abuf,
    const int* __restrict__ rowptr, const int* __restrict__ src_sorted,
    const float* __restrict__ y_csr, const __half* __restrict__ wgtbuf,
    int N, int l)
{
  __shared__ __align__(16) float smem[3328];
  float (*sF)[240] = (float(*)[240])smem;
  float (*sY)[12]  = (float(*)[12])(smem + 1920);
  __half* sWG      = (__half*)(smem + 2048);

  int t = threadIdx.x;
  int w = t>>6, lane = t&63;
  int n = blockIdx.x;
  int rs = rowptr[n], re = rowptr[n+1];

  // ---- per-thread component mapping for c = t + 256*q ----
  // spec: -1 inactive | 1 single product | 0 cross (2 products) | 2 dot3 | 3 dot5
  int widx[4], off0[4], off1[4], ds0[4], ds1[4], spec[4], opos[4];
  #pragma unroll
  for (int q=0;q<4;q++){
    int c = t + 256*q;
    spec[q] = -1; widx[q]=0; off0[q]=0; off1[q]=0; ds0[q]=8; ds1[q]=9; opos[q]=0;
    if (c < 64){            // a0 scalar : w0*s (Y0==1)
      spec[q]=1; widx[q]=c; off0[q]=c; opos[q]=c;
    } else if (c < 96){     // a0 vec dot Y1..3
      spec[q]=2; widx[q]=c; off0[q]=64+(c-64)*3; opos[q]=c;
    } else if (c < 112){    // a0 tensor dot Y4..8
      spec[q]=3; widx[q]=c; off0[q]=160+(c-96)*5; opos[q]=c;
    } else if (c < 496){
      int rr=c-112, row=rr/3, dd=rr-row*3;
      opos[q] = 112 + dd*128 + row;       // d-major a1
      if (row < 64){        // w1s * s * Y(1+dd)
        spec[q]=1; widx[q]=112+row; off0[q]=row; ds0[q]=dd;
      } else if (row < 96){ // w1v * v  (Y0==1)
        spec[q]=1; widx[q]=176+(row-64); off0[q]=64+(row-64)*3+dd;
      } else {              // w1x * cross(v, y)
        int cc=row-96;
        int d1=dd+1; if (d1>2) d1-=3;
        int d2=dd+2; if (d2>2) d2-=3;
        spec[q]=0; widx[q]=208+cc; off0[q]=64+cc*3+d1; ds0[q]=d2; off1[q]=64+cc*3+d2; ds1[q]=d1;
      }
    } else if (c < 896){
      int rr=c-496, row=rr/5, dd=rr-row*5;
      opos[q] = 496 + dd*80 + row;        // d-major a2
      if (row < 64){        // w2s * s * Y(4+dd)
        spec[q]=1; widx[q]=240+row; off0[q]=row; ds0[q]=3+dd;
      } else {              // w2t * t (Y0==1)
        spec[q]=1; widx[q]=304+(row-64); off0[q]=160+(row-64)*5+dd;
      }
    }
  }

  // ---- zero-init sF/sY (pad rows must be finite; wg=0 kills them) ----
  for (int i=t; i<2016; i+=256) smem[i] = 0.f;
  __syncthreads();

  float racc[4] = {0.f,0.f,0.f,0.f};

  for (int ch = rs; ch < re; ch += GC){
    int cnt = min(GC, re-ch);
    // ---- stage features + Y (wave w handles edges w and w+4) ----
    #pragma unroll
    for (int rep=0; rep<2; rep++){
      int e = w + rep*4;
      if (e < cnt){
        int j = ch + e;
        int s_ = src_sorted[j];
        #pragma unroll
        for (int qq = 0; qq < 4; qq++){
          int idx = lane + qq*64;
          if (idx < 240){
            float v;
            if (idx < 64)       v = hs0[(size_t)s_*64 + idx];
            else if (idx < 160) v = hv0[(size_t)s_*96 + (idx-64)];
            else                v = ht0[(size_t)s_*80 + (idx-160)];
            sF[e][idx] = v;
          }
        }
        if (lane < 10) sY[e][lane] = (lane < 8) ? y_csr[(size_t)j*8 + lane] : (lane==8 ? 1.f : 0.f);
      }
    }
    // ---- stage wgt rows (contiguous in CSR order) + zero pad rows, uint4 ----
    {
      const uint4* gsrc = (const uint4*)(wgtbuf + (size_t)ch*320);
      uint4* ldst = (uint4*)sWG;
      int tot4 = cnt*40;
      for (int i=t; i<tot4; i+=256) ldst[i] = gsrc[i];
      uint4 z4; z4.x=0u; z4.y=0u; z4.z=0u; z4.w=0u;
      for (int i=tot4+t; i<GC*40; i+=256) ldst[i] = z4;
    }
    __syncthreads();

    // ---- accumulate: 2-granular padded unroll ----
    ACC_JJ(0) ACC_JJ(1)
    if (cnt > 2){
      ACC_JJ(2) ACC_JJ(3)
      if (cnt > 4){
        ACC_JJ(4) ACC_JJ(5)
        if (cnt > 6){
          ACC_JJ(6) ACC_JJ(7)
        }
      }
    }
    __syncthreads();
  }

  // ---- write aggregated messages (d-major permutation) ----
  float* ap = abuf + (size_t)n*896;
  ap[opos[0]] = racc[0];
  ap[opos[1]] = racc[1];
  ap[opos[2]] = racc[2];
  if (t < 128) ap[opos[3]] = racc[3];
}

// ---------------- k_update: barrier-free streaming, 4 nodes per thread ----------------
#define FMA4(acc, s, wv4) { acc.x += (s)*(wv4).x; acc.y += (s)*(wv4).y; acc.z += (s)*(wv4).z; acc.w += (s)*(wv4).w; }

__global__ __launch_bounds__(256) void k_update(
    const float* __restrict__ hs0, const float* __restrict__ hv0, const float* __restrict__ ht0,
    float* __restrict__ hs1, float* __restrict__ hv1, float* __restrict__ ht1,
    const float* __restrict__ abuf,
    const float* __restrict__ Ws, const float* __restrict__ Wss,
    const float* __restrict__ Wv, const float* __restrict__ Wvv,
    const float* __restrict__ Wt, const float* __restrict__ Wtt,
    int N, int l)
{
  int nquads = (N+3)>>2;
  int task = blockIdx.x*256 + threadIdx.x;
  int limA = nquads*16, limB = nquads*40, limC = nquads*60;

  if (task < limA){
    int nq = task >> 4, fg = task & 15;
    int n0 = nq*4;
    int m1 = min(n0+1,N-1), m2 = min(n0+2,N-1), m3 = min(n0+3,N-1);
    const float4* A0 = (const float4*)(abuf + (size_t)n0*896);
    const float4* A1 = (const float4*)(abuf + (size_t)m1*896);
    const float4* A2 = (const float4*)(abuf + (size_t)m2*896);
    const float4* A3 = (const float4*)(abuf + (size_t)m3*896);
    const float* Wsg = Ws + (size_t)l*112*64 + fg*4;
    float4 c0={0.f,0.f,0.f,0.f}, c1=c0, c2=c0, c3=c0;
    #pragma unroll 2
    for (int cb=0; cb<28; cb++){
      const float* wp = Wsg + (size_t)(cb*4)*64;
      float4 w0 = *(const float4*)(wp);
      float4 w1 = *(const float4*)(wp+64);
      float4 w2 = *(const float4*)(wp+128);
      float4 w3 = *(const float4*)(wp+192);
      float4 a0 = A0[cb], a1 = A1[cb], a2 = A2[cb], a3 = A3[cb];
      FMA4(c0,a0.x,w0); FMA4(c0,a0.y,w1); FMA4(c0,a0.z,w2); FMA4(c0,a0.w,w3);
      FMA4(c1,a1.x,w0); FMA4(c1,a1.y,w1); FMA4(c1,a1.z,w2); FMA4(c1,a1.w,w3);
      FMA4(c2,a2.x,w0); FMA4(c2,a2.y,w1); FMA4(c2,a2.z,w2); FMA4(c2,a2.w,w3);
      FMA4(c3,a3.x,w0); FMA4(c3,a3.y,w1); FMA4(c3,a3.z,w2); FMA4(c3,a3.w,w3);
    }
    const float4* H0 = (const float4*)(hs0 + (size_t)n0*64);
    const float4* H1 = (const float4*)(hs0 + (size_t)m1*64);
    const float4* H2 = (const float4*)(hs0 + (size_t)m2*64);
    const float4* H3 = (const float4*)(hs0 + (size_t)m3*64);
    const float* Wssg = Wss + (size_t)l*64*64 + fg*4;
    #pragma unroll 2
    for (int cb=0; cb<16; cb++){
      const float* wp = Wssg + (size_t)(cb*4)*64;
      float4 w0 = *(const float4*)(wp);
      float4 w1 = *(const float4*)(wp+64);
      float4 w2 = *(const float4*)(wp+128);
      float4 w3 = *(const float4*)(wp+192);
      float4 a0 = H0[cb], a1 = H1[cb], a2 = H2[cb], a3 = H3[cb];
      FMA4(c0,a0.x,w0); FMA4(c0,a0.y,w1); FMA4(c0,a0.z,w2); FMA4(c0,a0.w,w3);
      FMA4(c1,a1.x,w0); FMA4(c1,a1.y,w1); FMA4(c1,a1.z,w2); FMA4(c1,a1.w,w3);
      FMA4(c2,a2.x,w0); FMA4(c2,a2.y,w1); FMA4(c2,a2.z,w2); FMA4(c2,a2.w,w3);
      FMA4(c3,a3.x,w0); FMA4(c3,a3.y,w1); FMA4(c3,a3.z,w2); FMA4(c3,a3.w,w3);
    }
    float4 o;
    o.x=silu_f(c0.x); o.y=silu_f(c0.y); o.z=silu_f(c0.z); o.w=silu_f(c0.w);
    *(float4*)(hs1 + (size_t)n0*64 + fg*4) = o;
    if (n0+1 < N){ o.x=silu_f(c1.x); o.y=silu_f(c1.y); o.z=silu_f(c1.z); o.w=silu_f(c1.w); *(float4*)(hs1 + (size_t)(n0+1)*64 + fg*4) = o; }
    if (n0+2 < N){ o.x=silu_f(c2.x); o.y=silu_f(c2.y); o.z=silu_f(c2.z); o.w=silu_f(c2.w); *(float4*)(hs1 + (size_t)(n0+2)*64 + fg*4) = o; }
    if (n0+3 < N){ o.x=silu_f(c3.x); o.y=silu_f(c3.y); o.z=silu_f(c3.z); o.w=silu_f(c3.w); *(float4*)(hs1 + (size_t)(n0+3)*64 + fg*4) = o; }
  } else if (task < limB){
    int tB = task - limA;
    int nq = tB / 24, r = tB - nq*24;
    int d = r >> 3, fg = r & 7;          // f = fg*4
    int n0 = nq*4;
    int m1 = min(n0+1,N-1), m2 = min(n0+2,N-1), m3 = min(n0+3,N-1);
    const float4* A0 = (const float4*)(abuf + (size_t)n0*896 + 112 + d*128);
    const float4* A1 = (const float4*)(abuf + (size_t)m1*896 + 112 + d*128);
    const float4* A2 = (const float4*)(abuf + (size_t)m2*896 + 112 + d*128);
    const float4* A3 = (const float4*)(abuf + (size_t)m3*896 + 112 + d*128);
    const float* Wvg = Wv + (size_t)l*128*32 + fg*4;
    float4 c0={0.f,0.f,0.f,0.f}, c1=c0, c2=c0, c3=c0;
    #pragma unroll 2
    for (int cb=0; cb<32; cb++){
      const float* wp = Wvg + (size_t)(cb*4)*32;
      float4 w0 = *(const float4*)(wp);
      float4 w1 = *(const float4*)(wp+32);
      float4 w2 = *(const float4*)(wp+64);
      float4 w3 = *(const float4*)(wp+96);
      float4 a0 = A0[cb], a1 = A1[cb], a2 = A2[cb], a3 = A3[cb];
      FMA4(c0,a0.x,w0); FMA4(c0,a0.y,w1); FMA4(c0,a0.z,w2); FMA4(c0,a0.w,w3);
      FMA4(c1,a1.x,w0); FMA4(c1,a1.y,w1); FMA4(c1,a1.z,w2); FMA4(c1,a1.w,w3);
      FMA4(c2,a2.x,w0); FMA4(c2,a2.y,w1); FMA4(c2,a2.z,w2); FMA4(c2,a2.w,w3);
      FMA4(c3,a3.x,w0); FMA4(c3,a3.y,w1); FMA4(c3,a3.z,w2); FMA4(c3,a3.w,w3);
    }
    const float* h0 = hv0 + (size_t)n0*96 + d;
    const float* h1 = hv0 + (size_t)m1*96 + d;
    const float* h2 = hv0 + (size_t)m2*96 + d;
    const float* h3 = hv0 + (size_t)m3*96 + d;
    const float* Wvvg = Wvv + (size_t)l*32*32 + fg*4;
    #pragma unroll 2
    for (int cc=0; cc<32; cc++){
      float4 wv4 = *(const float4*)(Wvvg + (size_t)cc*32);
      float a0 = h0[cc*3], a1 = h1[cc*3], a2 = h2[cc*3], a3 = h3[cc*3];
      FMA4(c0,a0,wv4); FMA4(c1,a1,wv4); FMA4(c2,a2,wv4); FMA4(c3,a3,wv4);
    }
    int f = fg*4;
    {
      float* op = hv1 + (size_t)n0*96 + d;
      op[(f+0)*3]=c0.x; op[(f+1)*3]=c0.y; op[(f+2)*3]=c0.z; op[(f+3)*3]=c0.w;
    }
    if (n0+1 < N){ float* op = hv1 + (size_t)(n0+1)*96 + d; op[(f+0)*3]=c1.x; op[(f+1)*3]=c1.y; op[(f+2)*3]=c1.z; op[(f+3)*3]=c1.w; }
    if (n0+2 < N){ float* op = hv1 + (size_t)(n0+2)*96 + d; op[(f+0)*3]=c2.x; op[(f+1)*3]=c2.y; op[(f+2)*3]=c2.z; op[(f+3)*3]=c2.w; }
    if (n0+3 < N){ float* op = hv1 + (size_t)(n0+3)*96 + d; op[(f+0)*3]=c3.x; op[(f+1)*3]=c3.y; op[(f+2)*3]=c3.z; op[(f+3)*3]=c3.w; }
  } else if (task < limC){
    int tC = task - limB;
    int nq = tC / 20, r = tC - nq*20;
    int d = r >> 2, fg = r & 3;          // f = fg*4
    int n0 = nq*4;
    int m1 = min(n0+1,N-1), m2 = min(n0+2,N-1), m3 = min(n0+3,N-1);
    const float4* A0 = (const float4*)(abuf + (size_t)n0*896 + 496 + d*80);
    const float4* A1 = (const float4*)(abuf + (size_t)m1*896 + 496 + d*80);
    const float4* A2 = (const float4*)(abuf + (size_t)m2*896 + 496 + d*80);
    const float4* A3 = (const float4*)(abuf + (size_t)m3*896 + 496 + d*80);
    const float* Wtg = Wt + (size_t)l*80*16 + fg*4;
    float4 c0={0.f,0.f,0.f,0.f}, c1=c0, c2=c0, c3=c0;
    #pragma unroll 2
    for (int cb=0; cb<20; cb++){
      const float* wp = Wtg + (size_t)(cb*4)*16;
      float4 w0 = *(const float4*)(wp);
      float4 w1 = *(const float4*)(wp+16);
      float4 w2 = *(const float4*)(wp+32);
      float4 w3 = *(const float4*)(wp+48);
      float4 a0 = A0[cb], a1 = A1[cb], a2 = A2[cb], a3 = A3[cb];
      FMA4(c0,a0.x,w0); FMA4(c0,a0.y,w1); FMA4(c0,a0.z,w2); FMA4(c0,a0.w,w3);
      FMA4(c1,a1.x,w0); FMA4(c1,a1.y,w1); FMA4(c1,a1.z,w2); FMA4(c1,a1.w,w3);
      FMA4(c2,a2.x,w0); FMA4(c2,a2.y,w1); FMA4(c2,a2.z,w2); FMA4(c2,a2.w,w3);
      FMA4(c3,a3.x,w0); FMA4(c3,a3.y,w1); FMA4(c3,a3.z,w2); FMA4(c3,a3.w,w3);
    }
    const float* h0 = ht0 + (size_t)n0*80 + d;
    const float* h1 = ht0 + (size_t)m1*80 + d;
    const float* h2 = ht0 + (size_t)m2*80 + d;
    const float* h3 = ht0 + (size_t)m3*80 + d;
    const float* Wttg = Wtt + (size_t)l*16*16 + fg*4;
    #pragma unroll 2
    for (int cc=0; cc<16; cc++){
      float4 wv4 = *(const float4*)(Wttg + (size_t)cc*16);
      float a0 = h0[cc*5], a1 = h1[cc*5], a2 = h2[cc*5], a3 = h3[cc*5];
      FMA4(c0,a0,wv4); FMA4(c1,a1,wv4); FMA4(c2,a2,wv4); FMA4(c3,a3,wv4);
    }
    int f = fg*4;
    {
      float* op = ht1 + (size_t)n0*80 + d;
      op[(f+0)*5]=c0.x; op[(f+1)*5]=c0.y; op[(f+2)*5]=c0.z; op[(f+3)*5]=c0.w;
    }
    if (n0+1 < N){ float* op = ht1 + (size_t)(n0+1)*80 + d; op[(f+0)*5]=c1.x; op[(f+1)*5]=c1.y; op[(f+2)*5]=c1.z; op[(f+3)*5]=c1.w; }
    if (n0+2 < N){ float* op = ht1 + (size_t)(n0+2)*80 + d; op[(f+0)*5]=c2.x; op[(f+1)*5]=c2.y; op[(f+2)*5]=c2.z; op[(f+3)*5]=c2.w; }
    if (n0+3 < N){ float* op = ht1 + (size_t)(n0+3)*80 + d; op[(f+0)*5]=c3.x; op[(f+1)*5]=c3.y; op[(f+2)*5]=c3.z; op[(f+3)*5]=c3.w; }
  }
}

// ---------------- readout ----------------
__global__ __launch_bounds__(64) void k_q(const float* __restrict__ hs, const int* __restrict__ absorber,
                                          const float* __restrict__ Wq, float* __restrict__ qbuf, int G){
  __shared__ float sH[64];
  int g = blockIdx.x, f = threadIdx.x;
  int a = absorber[g];
  sH[f] = hs[(size_t)a*64+f];
  __syncthreads();
  float acc = 0.f;
  for (int c=0;c<64;c++) acc += sH[c]*Wq[c*64+f];
  qbuf[(size_t)g*64+f] = acc;
}

__global__ __launch_bounds__(64) void k_kv(const float* __restrict__ hs,
                                           const float* __restrict__ Wk, const float* __restrict__ Wvp,
                                           float* __restrict__ kbuf, float* __restrict__ vbuf, int N){
  __shared__ float sH[8][64];
  int t = threadIdx.x;
  int n0 = blockIdx.x*8;
  int nmax = min(8, N-n0);
  for (int idx=t; idx<nmax*64; idx+=64){ int n=idx>>6, c=idx&63; sH[n][c]=hs[(size_t)(n0+n)*64+c]; }
  __syncthreads();
  float ka[8], va[8];
  #pragma unroll
  for (int n=0;n<8;n++){ ka[n]=0.f; va[n]=0.f; }
  for (int c=0;c<64;c++){
    float wk = Wk[c*64+t], wv = Wvp[c*64+t];
    #pragma unroll
    for (int n=0;n<8;n++){ ka[n]+=sH[n][c]*wk; va[n]+=sH[n][c]*wv; }
  }
  for (int n=0;n<nmax;n++){ kbuf[(size_t)(n0+n)*64+t]=ka[n]; vbuf[(size_t)(n0+n)*64+t]=va[n]; }
}

__global__ __launch_bounds__(256) void k_logit(const float* __restrict__ kbuf, const float* __restrict__ qbuf,
                                               const int* __restrict__ batch,
                                               float* __restrict__ logitbuf, unsigned* __restrict__ mkey, int N){
  int wave = threadIdx.x>>6, lane = threadIdx.x&63;
  int n = blockIdx.x*4 + wave;
  if (n >= N) return;
  int g = batch[n];
  float p = kbuf[(size_t)n*64+lane]*qbuf[(size_t)g*64+lane];
  #pragma unroll
  for (int off=32; off>0; off>>=1) p += __shfl_down(p, off, 64);
  if (lane==0){
    float logit = p*0.125f;
    logitbuf[n] = logit;
    unsigned u = __float_as_uint(logit);
    unsigned key = (u & 0x80000000u) ? ~u : (u | 0x80000000u);
    atomicMax(&mkey[g], key);
  }
}

__global__ __launch_bounds__(256) void k_soft(const float* __restrict__ vbuf, const float* __restrict__ logitbuf,
                                              const int* __restrict__ batch, const unsigned* __restrict__ mkey,
                                              float* __restrict__ den, float* __restrict__ cbuf, int N){
  int wave = threadIdx.x>>6, lane = threadIdx.x&63;
  int n = blockIdx.x*4 + wave;
  if (n >= N) return;
  int g = batch[n];
  unsigned key = mkey[g];
  unsigned u = (key & 0x80000000u) ? (key ^ 0x80000000u) : ~key;
  float m = __uint_as_float(u);
  float ex = __expf(logitbuf[n] - m);
  if (lane==0) atomicAdd(&den[g], ex);
  atomicAdd(&cbuf[(size_t)g*64+lane], ex*vbuf[(size_t)n*64+lane]);
}

__global__ __launch_bounds__(192) void k_final(const float* __restrict__ hs, const float* __restrict__ hv,
                                               const float* __restrict__ ht, const int* __restrict__ absorber,
                                               const float* __restrict__ den, const float* __restrict__ cbuf,
                                               const float* __restrict__ Wr1, const float* __restrict__ br1,
                                               const float* __restrict__ Wr2, const float* __restrict__ br2,
                                               float* __restrict__ out, int G){
  __shared__ float zr[176];
  __shared__ float h1[128];
  int g = blockIdx.x, t = threadIdx.x;
  int a = absorber[g];
  if (t < 64) zr[t] = hs[(size_t)a*64+t];
  else if (t < 128){
    int f = t-64;
    zr[t] = cbuf[(size_t)g*64+f] / fmaxf(den[g], 1e-9f);
  } else if (t < 160){
    int j = t-128; float s = 0.f;
    #pragma unroll
    for (int dd=0;dd<3;dd++){ float v = hv[(size_t)a*96+j*3+dd]; s += v*v; }
    zr[t] = s;
  } else if (t < 176){
    int j = t-160; float s = 0.f;
    #pragma unroll
    for (int dd=0;dd<5;dd++){ float v = ht[(size_t)a*80+j*5+dd]; s += v*v; }
    zr[t] = s;
  }
  __syncthreads();
  if (t < 128){
    float acc = br1[t];
    for (int i=0;i<176;i++) acc += zr[i]*Wr1[i*128+t];
    h1[t] = silu_f(acc);
  }
  __syncthreads();
  if (t < 128){
    float acc = br2[t];
    for (int j=0;j<128;j++) acc += h1[j]*Wr2[j*128+t];
    out[(size_t)g*128+t] = acc;
  }
}

extern "C" void kernel_launch(void* const* d_in, const int* in_sizes, int n_in,
                              void* d_out, int out_size, void* d_ws, size_t ws_size,
                              hipStream_t stream){
  const int*   z        = (const int*)  d_in[0];
  const float* pos      = (const float*)d_in[1];
  const int*   ei       = (const int*)  d_in[2];
  const int*   batch    = (const int*)  d_in[3];
  const int*   absorber = (const int*)  d_in[4];
  const float* embed    = (const float*)d_in[5];
  const float* rW1      = (const float*)d_in[6];
  const float* rb1      = (const float*)d_in[7];
  const float* rW2      = (const float*)d_in[8];
  const float* Ws       = (const float*)d_in[9];
  const float* Wss      = (const float*)d_in[10];
  const float* Wv       = (const float*)d_in[11];
  const float* Wvv      = (const float*)d_in[12];
  const float* Wt       = (const float*)d_in[13];
  const float* Wtt      = (const float*)d_in[14];
  const float* Wq       = (const float*)d_in[15];
  const float* Wk       = (const float*)d_in[16];
  const float* Wvp      = (const float*)d_in[17];
  const float* Wr1      = (const float*)d_in[18];
  const float* br1      = (const float*)d_in[19];
  const float* Wr2      = (const float*)d_in[20];
  const float* br2      = (const float*)d_in[21];

  int N = in_sizes[0];
  int E = in_sizes[2]/2;
  int G = in_sizes[4];
  const int* srcArr = ei;
  const int* dstArr = ei + E;

  float* p = (float*)d_ws;
  float* hsA   = p; p += (size_t)N*64;
  float* hvA   = p; p += (size_t)N*96;
  float* htA   = p; p += (size_t)N*80;
  float* hsB   = p; p += (size_t)N*64;
  float* hvB   = p; p += (size_t)N*96;
  float* htB   = p; p += (size_t)N*80;
  float* rb_csr= p; p += (size_t)E*10;
  float* y_csr = p; p += (size_t)E*8;
  unsigned* mkey = (unsigned*)p; p += G;
  float* den   = p; p += G;
  float* cbuf  = p; p += (size_t)G*64;
  int* deg     = (int*)p; p += N;
  int* rowptr  = (int*)p; p += (N+1);
  int* cursor  = (int*)p; p += N;
  int* inv     = (int*)p; p += E;
  int* src_sorted = (int*)p; p += E;
  int* bsum    = (int*)p; p += 256;
  int* boff    = (int*)p; p += 256;
  p += ((8 - (((uintptr_t)p >> 2) & 7)) & 7);   // 32B align
  __half* wgtbuf = (__half*)p;                   // E*320 halves = E*160 floats
  float* kbuf    = (float*)wgtbuf;               // readout aliases (post-layers)
  float* vbuf    = kbuf + (size_t)N*64;
  float* qbuf    = vbuf + (size_t)N*64;
  float* logitbuf= qbuf + (size_t)G*64;
  p += (size_t)E*160;
  float* abuf  = p; p += (size_t)N*896;

  int nb = (N + 255)/256;
  int initTot = N*96;
  k_init<<<(initTot+255)/256, 256, 0, stream>>>(z, embed, hsA, hvA, htA, deg, mkey, den, cbuf, N, G);
  k_deg<<<(E+255)/256, 256, 0, stream>>>(dstArr, deg, E);
  k_scanA<<<nb, 256, 0, stream>>>(deg, bsum, N);
  k_scanB<<<1, 256, 0, stream>>>(bsum, boff, nb);
  k_scanC<<<nb, 256, 0, stream>>>(deg, boff, rowptr, cursor, N);
  k_fill<<<(E+255)/256, 256, 0, stream>>>(dstArr, srcArr, cursor, inv, src_sorted, E);
  k_efeat<<<(E+255)/256, 256, 0, stream>>>(pos, srcArr, dstArr, inv, rb_csr, y_csr, E);

  float *hsO=hsA, *hvO=hvA, *htO=htA, *hsN=hsB, *hvN=hvB, *htN=htB;
  int nquads = (N+3)/4;
  int updBlocks = (nquads*60 + 255)/256;
  for (int l=0; l<NLAYERS; l++){
    k_wgt<<<(E+TILE_E-1)/TILE_E, 320, 0, stream>>>(rb_csr, rW1, rb1, rW2, wgtbuf, E, l);
    k_gather<<<N, 256, 0, stream>>>(hsO, hvO, htO, abuf,
                                    rowptr, src_sorted, y_csr, wgtbuf, N, l);
    k_update<<<updBlocks, 256, 0, stream>>>(hsO, hvO, htO, hsN, hvN, htN, abuf,
                                            Ws, Wss, Wv, Wvv, Wt, Wtt, N, l);
    float* tp;
    tp=hsO; hsO=hsN; hsN=tp;
    tp=hvO; hvO=hvN; hvN=tp;
    tp=htO; htO=htN; htN=tp;
  }

  k_q<<<G, 64, 0, stream>>>(hsO, absorber, Wq, qbuf, G);
  k_kv<<<(N+7)/8, 64, 0, stream>>>(hsO, Wk, Wvp, kbuf, vbuf, N);
  k_logit<<<(N+3)/4, 256, 0, stream>>>(kbuf, qbuf, batch, logitbuf, mkey, N);
  k_soft<<<(N+3)/4, 256, 0, stream>>>(vbuf, logitbuf, batch, mkey, den, cbuf, N);
  k_final<<<G, 192, 0, stream>>>(hsO, hvO, htO, absorber, den, cbuf, Wr1, br1, Wr2, br2, (float*)d_out, G);
}